// Round 1
// baseline (272.016 us; speedup 1.0000x reference)
//
#include <hip/hip_runtime.h>

// Problem constants (fixed by the reference):
//   B=128, L=9, K=3, C_IN=C_OUT=256, P=1680 (perms of [0,0,0,1,1,1,2,2,2], lex order)
#define B_DIM 128
#define L_DIM 9
#define K_DIM 3
#define C 256
#define P_TOT 1680
#define R_DIM 27          // L*K rows of Z per batch
#define CHUNK 210         // p's per stream block (8 chunks per b)

// Workspace layout (bytes):
//   [0, 13440)              packed : uint2[P] — 9 row indices (5b each) + dpos<<15
//   [16384, 16384+768K)     Wt     : float[3*256*256], Wt[a][c][o] = W[a][o][c]
//   [1M, 1M+3.456M)         Z      : float[128*27*256], Z[b][l*3+a][o]
#define WS_WT_OFF 16384
#define WS_Z_OFF  (1u << 20)

typedef float vfloat4 __attribute__((ext_vector_type(4)));  // for nontemporal stores

__device__ inline float4 add4(float4 a, float4 b) {
    return make_float4(a.x + b.x, a.y + b.y, a.z + b.z, a.w + b.w);
}

// --------------------------------------------------------------- setup ----
// blocks 0..6   : packed[p] from one-hot M (idx = M1 + 2*M2), dpos vs perm p-1
// blocks 7..198 : W transpose -> Wt[a][c][o] so z_kernel's W stream is
//                 lane-coalesced (lanes along o).  1.5 MB total, ~5 us.
__global__ __launch_bounds__(256) void setup_kernel(const float* __restrict__ M,
                                                    const float* __restrict__ W,
                                                    uint2* __restrict__ packed,
                                                    float* __restrict__ Wt) {
    int bid = blockIdx.x;
    int t = threadIdx.x;
    if (bid < 7) {
        int p = bid * 256 + t;
        if (p >= P_TOT) return;
        unsigned rows[L_DIM];
#pragma unroll
        for (int l = 0; l < L_DIM; ++l) {
            float m1 = M[(1 * P_TOT + p) * L_DIM + l];
            float m2 = M[(2 * P_TOT + p) * L_DIM + l];
            unsigned a = (unsigned)(m1 + 2.0f * m2 + 0.5f);
            rows[l] = (unsigned)(l * K_DIM) + a;
        }
        unsigned d = 0;
        if (p > 0) {
            while (d < L_DIM) {
                float m1 = M[(1 * P_TOT + (p - 1)) * L_DIM + d];
                float m2 = M[(2 * P_TOT + (p - 1)) * L_DIM + d];
                unsigned pr = d * K_DIM + (unsigned)(m1 + 2.0f * m2 + 0.5f);
                if (pr != rows[d]) break;
                ++d;
            }
        }
        unsigned lo = 0, hi = 0;
#pragma unroll
        for (int l = 0; l < 6; ++l) lo |= rows[l] << (5 * l);
#pragma unroll
        for (int l = 6; l < L_DIM; ++l) hi |= rows[l] << (5 * (l - 6));
        hi |= d << 15;
        packed[p] = make_uint2(lo, hi);
    } else {
        int tb = bid - 7;  // 0..191, each does 4 (a,c) rows of 256 o's
#pragma unroll
        for (int i = 0; i < 4; ++i) {
            int rowid = tb * 4 + i;          // 0..767
            int a = rowid >> 8;
            int c = rowid & 255;
            Wt[(a * C + c) * C + t] = W[(a * C + t) * C + c];
        }
    }
}

// ------------------------------------------------------------------- Z ----
// Z[b][l*3+a][o] = sum_c x[b,l,c] * Wt[a][c][o], computed ONCE per b (the old
// fused kernel recomputed it per half-block AND paid 576 uniform ds_read_b128
// broadcasts per wave — the LDS pipe, not FMA, was the phase-A cost).
// 256 blocks = (b, o-half) x 384 threads = (a 0..2, o' 0..127); no LDS:
//   - w loads lane-coalesced from Wt (lanes along o)
//   - x loads are wave-uniform addresses -> scalar s_load_dwordx4 path,
//     leaving the LDS unit completely idle and VALU as the only consumer.
// 453 MFLOP fp32 across the full GPU ~ 3-8 us.
__global__ __launch_bounds__(384) void z_kernel(const float* __restrict__ x,
                                                const float* __restrict__ Wt,
                                                float* __restrict__ Z) {
    int bid = blockIdx.x;            // 0..255 : (b, o-half)
    int b = bid >> 1;
    int t = threadIdx.x;             // 0..383
    int a = t >> 7;                  // 0..2 (all threads active)
    int o = ((bid & 1) << 7) + (t & 127);

    const float4* __restrict__ xb4 = (const float4*)(x + (size_t)b * (L_DIM * C));
    const float* __restrict__ wp = Wt + (size_t)a * C * C + o;

    float acc[L_DIM];
#pragma unroll
    for (int l = 0; l < L_DIM; ++l) acc[l] = 0.0f;

#pragma unroll 2
    for (int c4 = 0; c4 < C / 4; ++c4) {
        float w0 = wp[(4 * c4 + 0) * C];
        float w1 = wp[(4 * c4 + 1) * C];
        float w2 = wp[(4 * c4 + 2) * C];
        float w3 = wp[(4 * c4 + 3) * C];
#pragma unroll
        for (int l = 0; l < L_DIM; ++l) {
            float4 xv = xb4[l * (C / 4) + c4];   // uniform -> s_load_dwordx4
            acc[l] += xv.x * w0 + xv.y * w1 + xv.z * w2 + xv.w * w3;
        }
    }
#pragma unroll
    for (int l = 0; l < L_DIM; ++l)
        Z[((size_t)b * R_DIM + (l * K_DIM + a)) * C + o] = acc[l];
}

// -------------------------------------------------------------- stream ----
// Pure phase B: one block per (b, 210-p chunk); 1024 blocks x 256 threads ->
// 4 blocks/CU (29.3 KB LDS each), 16 waves/CU for store/LDS latency hiding.
// Stage Z[b] (27 KB, L2/L3-hot: 27.6 MB total re-read, trivial) + packed
// chunk; then per wave 52-53 consecutive p's with running prefix partials
// p0..p8 in registers, resume at dpos (lex prefix sharing: ~3.1 new rows/p);
// 1KB/wave nontemporal coalesced stores. Write-roofline ~35 us.
__global__ __launch_bounds__(256) void stream_kernel(const float* __restrict__ Z,
                                                     const uint2* __restrict__ packed,
                                                     float* __restrict__ out) {
    __shared__ float Zs[R_DIM * C];      // 27 KB
    __shared__ uint2 pk[CHUNK];          // 1.68 KB

    int bid = blockIdx.x;                // 0..1023
    int b = bid >> 3;
    int pstart = (bid & 7) * CHUNK;
    int t = threadIdx.x;

    // stage Z[b] (1728 float4) and this chunk's packed indices
    const float4* zg = (const float4*)(Z + (size_t)b * R_DIM * C);
#pragma unroll
    for (int k = 0; k < 7; ++k) {
        int idx = k * 256 + t;
        if (idx < R_DIM * C / 4) ((float4*)Zs)[idx] = zg[idx];
    }
    if (t < CHUNK) pk[t] = packed[pstart + t];
    __syncthreads();

    int wave = t >> 6;
    int lane = t & 63;
    const float4* zsr = (const float4*)Zs;
    vfloat4* out4 = (vfloat4*)out;

    int pb = (CHUNK * wave) >> 2;        // 0,52,105,157
    int pe = (CHUNK * (wave + 1)) >> 2;  // 52,105,157,210

    float4 p0, p1, p2, p3, p4, p5, p6, p7, p8;

    for (int pl = pb; pl < pe; ++pl) {
        uint2 w = pk[pl];                               // broadcast LDS read
        unsigned lo = __builtin_amdgcn_readfirstlane(w.x);
        unsigned hi = __builtin_amdgcn_readfirstlane(w.y);
        // wave-uniform resume depth: 0 for the wave's first p (prev p not ours)
        int k = (pl == pb) ? 0 : (int)(hi >> 15);
        switch (k) {
            case 0: p0 = zsr[(lo & 31u) * 64 + lane]; [[fallthrough]];
            case 1: p1 = add4(p0, zsr[((lo >> 5) & 31u) * 64 + lane]); [[fallthrough]];
            case 2: p2 = add4(p1, zsr[((lo >> 10) & 31u) * 64 + lane]); [[fallthrough]];
            case 3: p3 = add4(p2, zsr[((lo >> 15) & 31u) * 64 + lane]); [[fallthrough]];
            case 4: p4 = add4(p3, zsr[((lo >> 20) & 31u) * 64 + lane]); [[fallthrough]];
            case 5: p5 = add4(p4, zsr[((lo >> 25) & 31u) * 64 + lane]); [[fallthrough]];
            case 6: p6 = add4(p5, zsr[(hi & 31u) * 64 + lane]); [[fallthrough]];
            case 7: p7 = add4(p6, zsr[((hi >> 5) & 31u) * 64 + lane]); [[fallthrough]];
            case 8: p8 = add4(p7, zsr[((hi >> 10) & 31u) * 64 + lane]); break;
            default: break;
        }
        // coalesced 1KB/wave nontemporal store (write-once streaming output)
        size_t orow = (size_t)(b * P_TOT + pstart + pl);
        vfloat4 sv = {p8.x, p8.y, p8.z, p8.w};
        __builtin_nontemporal_store(sv, &out4[orow * 64 + lane]);
    }
}

// ------------------------------------------------------------------ launch --
extern "C" void kernel_launch(void* const* d_in, const int* in_sizes, int n_in,
                              void* d_out, int out_size, void* d_ws, size_t ws_size,
                              hipStream_t stream) {
    const float* x = (const float*)d_in[0];  // (128, 9, 256)
    const float* W = (const float*)d_in[1];  // (3, 256, 256)
    const float* M = (const float*)d_in[2];  // (3, 1680, 9)
    float* out = (float*)d_out;              // (128, 1680, 256)

    uint2* packed = (uint2*)d_ws;
    float* Wt = (float*)((char*)d_ws + WS_WT_OFF);
    float* Z = (float*)((char*)d_ws + WS_Z_OFF);

    setup_kernel<<<199, 256, 0, stream>>>(M, W, packed, Wt);
    z_kernel<<<256, 384, 0, stream>>>(x, Wt, Z);
    stream_kernel<<<1024, 256, 0, stream>>>(Z, packed, out);
}

// Round 2
// 262.848 us; speedup vs baseline: 1.0349x; 1.0349x over previous
//
#include <hip/hip_runtime.h>

// Problem constants (fixed by the reference):
//   B=128, L=9, K=3, C_IN=C_OUT=256, P=1680 (perms of [0,0,0,1,1,1,2,2,2], lex order)
#define B_DIM 128
#define L_DIM 9
#define K_DIM 3
#define C 256
#define P_TOT 1680
#define R_DIM 27          // L*K rows of Z per batch
#define CHUNK 420         // p's per stream block (4 chunks per b)
#define LUT_ROWS 39       // 4 pairs x 9 combos + 3 singles (position 8)

// Workspace layout (bytes):
//   [0, 6720)               pkg : u32[P] — five 6-bit LUT row indices per p
//   [16384, 16384+768K)     Wt  : float[3*256*256], Wt[a][c][o] = W[a][o][c]
//   [1M, 1M+3.456M)         Z   : float[128*27*256], Z[b][l*3+a][o]
#define WS_WT_OFF 16384
#define WS_Z_OFF  (1u << 20)

typedef float vfloat4 __attribute__((ext_vector_type(4)));  // for nontemporal stores

__device__ inline float4 add4(float4 a, float4 b) {
    return make_float4(a.x + b.x, a.y + b.y, a.z + b.z, a.w + b.w);
}

// --------------------------------------------------------------- setup ----
// blocks 0..6   : pkg[p] — per position l the type a_l = M1 + 2*M2; pack the
//                 five LUT indices: pair j -> j*9 + a_{2j}*3 + a_{2j+1} (0..35),
//                 single -> 36 + a_8.  Five 6-bit fields in one u32.
// blocks 7..198 : W transpose -> Wt[a][c][o] (z_kernel's W stream coalesced).
__global__ __launch_bounds__(256) void setup_kernel(const float* __restrict__ M,
                                                    const float* __restrict__ W,
                                                    unsigned* __restrict__ pkg,
                                                    float* __restrict__ Wt) {
    int bid = blockIdx.x;
    int t = threadIdx.x;
    if (bid < 7) {
        int p = bid * 256 + t;
        if (p >= P_TOT) return;
        unsigned a[L_DIM];
#pragma unroll
        for (int l = 0; l < L_DIM; ++l) {
            float m1 = M[(1 * P_TOT + p) * L_DIM + l];
            float m2 = M[(2 * P_TOT + p) * L_DIM + l];
            a[l] = (unsigned)(m1 + 2.0f * m2 + 0.5f);
        }
        unsigned w = 0;
#pragma unroll
        for (int j = 0; j < 4; ++j)
            w |= (unsigned)(j * 9 + a[2 * j] * 3 + a[2 * j + 1]) << (6 * j);
        w |= (36u + a[8]) << 24;
        pkg[p] = w;
    } else {
        int tb = bid - 7;  // 0..191, each does 4 (a,c) rows of 256 o's
#pragma unroll
        for (int i = 0; i < 4; ++i) {
            int rowid = tb * 4 + i;          // 0..767
            int aa = rowid >> 8;
            int c = rowid & 255;
            Wt[(aa * C + c) * C + t] = W[(aa * C + t) * C + c];
        }
    }
}

// ------------------------------------------------------------------- Z ----
// Z[b][l*3+a][o] = sum_c x[b,l,c] * Wt[a][c][o], once per b.
// 256 blocks = (b, o-half) x 384 threads = (a 0..2, o' 0..127); no LDS:
//   - w loads lane-coalesced from Wt (lanes along o)
//   - x loads wave-uniform -> scalar s_load path.  ~453 MFLOP, a few us.
__global__ __launch_bounds__(384) void z_kernel(const float* __restrict__ x,
                                                const float* __restrict__ Wt,
                                                float* __restrict__ Z) {
    int bid = blockIdx.x;            // 0..255 : (b, o-half)
    int b = bid >> 1;
    int t = threadIdx.x;             // 0..383
    int a = t >> 7;                  // 0..2 (all threads active)
    int o = ((bid & 1) << 7) + (t & 127);

    const float4* __restrict__ xb4 = (const float4*)(x + (size_t)b * (L_DIM * C));
    const float* __restrict__ wp = Wt + (size_t)a * C * C + o;

    float acc[L_DIM];
#pragma unroll
    for (int l = 0; l < L_DIM; ++l) acc[l] = 0.0f;

#pragma unroll 2
    for (int c4 = 0; c4 < C / 4; ++c4) {
        float w0 = wp[(4 * c4 + 0) * C];
        float w1 = wp[(4 * c4 + 1) * C];
        float w2 = wp[(4 * c4 + 2) * C];
        float w3 = wp[(4 * c4 + 3) * C];
#pragma unroll
        for (int l = 0; l < L_DIM; ++l) {
            float4 xv = xb4[l * (C / 4) + c4];   // uniform -> s_load_dwordx4
            acc[l] += xv.x * w0 + xv.y * w1 + xv.z * w2 + xv.w * w3;
        }
    }
#pragma unroll
    for (int l = 0; l < L_DIM; ++l)
        Z[((size_t)b * R_DIM + (l * K_DIM + a)) * C + o] = acc[l];
}

// -------------------------------------------------------------- stream ----
// The old phase-B loop was latency-bound: per-p LDS round trip for the packed
// word -> readfirstlane -> switch branch -> prefix chain across iterations
// (~340 stalled cyc/p, all pipes <30% busy).  New scheme:
//   LUT build (once per block): LUT[j*9+a0*3+a1][o] = Z[6j+a0][o]+Z[6j+3+a1][o]
//   for the 4 position-pairs (36 rows) + 3 raw rows for position 8 -> 39 KB.
//   Per p: ONE u32 -> five 6-bit indices -> 5 independent ds_read_b128
//   + 4 adds + 1 nontemporal 1KB/wave store.  Branchless, no cross-iteration
//   deps, unroll 2 -> 10 reads in flight.  LDS-pipe ~23 us, stores ~35 us
//   (overlapping pipes) -> ~40 us target.
// 512 blocks (b x 4 chunks) x 512 threads; 41.6 KB LDS -> 3 blocks/CU,
// 24 waves/CU.
__global__ __launch_bounds__(512) void stream_kernel(const float* __restrict__ Z,
                                                     const unsigned* __restrict__ pkg,
                                                     float* __restrict__ out) {
    __shared__ float lut[LUT_ROWS * C];   // 39 KB
    __shared__ unsigned pk[CHUNK];        // 1.68 KB

    int bid = blockIdx.x;                 // 0..511
    int b = bid >> 2;
    int pstart = (bid & 3) * CHUNK;
    int t = threadIdx.x;

    // build the pair-sum LUT straight from global Z (L2/L3-hot, 27 KB/b)
    const float4* zg = (const float4*)(Z + (size_t)b * R_DIM * C);
    float4* lutw = (float4*)lut;
#pragma unroll
    for (int it = 0; it < 5; ++it) {      // 5*512 = 2560 >= 39*64 = 2496
        int idx = it * 512 + t;
        if (idx < LUT_ROWS * 64) {
            int r = idx >> 6, q = idx & 63;
            float4 v;
            if (r < 36) {
                int j = r / 9;
                int cmb = r - j * 9;
                int a0 = cmb / 3;
                int a1 = cmb - a0 * 3;
                v = add4(zg[(6 * j + a0) * 64 + q], zg[(6 * j + 3 + a1) * 64 + q]);
            } else {
                v = zg[(24 + r - 36) * 64 + q];
            }
            lutw[idx] = v;
        }
    }
    if (t < CHUNK) pk[t] = pkg[pstart + t];
    __syncthreads();

    int wave = t >> 6;
    int lane = t & 63;
    const float4* lutr = (const float4*)lut;
    vfloat4* out4 = (vfloat4*)out;

    int pb = (CHUNK * wave) >> 3;         // 52.5 p's per wave
    int pe = (CHUNK * (wave + 1)) >> 3;

#pragma unroll 2
    for (int pl = pb; pl < pe; ++pl) {
        unsigned w = __builtin_amdgcn_readfirstlane(pk[pl]);  // broadcast read
        float4 v0 = lutr[((w)&63u) * 64 + lane];
        float4 v1 = lutr[((w >> 6) & 63u) * 64 + lane];
        float4 v2 = lutr[((w >> 12) & 63u) * 64 + lane];
        float4 v3 = lutr[((w >> 18) & 63u) * 64 + lane];
        float4 v4 = lutr[((w >> 24) & 63u) * 64 + lane];
        float4 s = add4(add4(add4(v0, v1), add4(v2, v3)), v4);
        // coalesced 1KB/wave nontemporal store (write-once streaming output)
        size_t orow = (size_t)(b * P_TOT + pstart + pl);
        vfloat4 sv = {s.x, s.y, s.z, s.w};
        __builtin_nontemporal_store(sv, &out4[orow * 64 + lane]);
    }
}

// ------------------------------------------------------------------ launch --
extern "C" void kernel_launch(void* const* d_in, const int* in_sizes, int n_in,
                              void* d_out, int out_size, void* d_ws, size_t ws_size,
                              hipStream_t stream) {
    const float* x = (const float*)d_in[0];  // (128, 9, 256)
    const float* W = (const float*)d_in[1];  // (3, 256, 256)
    const float* M = (const float*)d_in[2];  // (3, 1680, 9)
    float* out = (float*)d_out;              // (128, 1680, 256)

    unsigned* pkg = (unsigned*)d_ws;
    float* Wt = (float*)((char*)d_ws + WS_WT_OFF);
    float* Z = (float*)((char*)d_ws + WS_Z_OFF);

    setup_kernel<<<199, 256, 0, stream>>>(M, W, pkg, Wt);
    z_kernel<<<256, 384, 0, stream>>>(x, Wt, Z);
    stream_kernel<<<512, 512, 0, stream>>>(Z, pkg, out);
}